// Round 1
// baseline (685.143 us; speedup 1.0000x reference)
//
#include <hip/hip_runtime.h>

// Problem constants (fixed by setup_inputs): N=2048, D=512, H=8, dh=64, max_iter=5.

// ---------------------------------------------------------------------------
// GEMM NT: C[i,j] = scale * sum_k A[i,k]*B[j,k] (+ bias[j])
// 64x64 tile per block, 256 threads, 4x4 micro-tile, K-tile 16.
// blockIdx.z offsets pointers by aoz/boz/coz (for per-head batched use).
// scale = 1/(8*t) when tptr != nullptr (scores), else 1.
// ---------------------------------------------------------------------------
__global__ __launch_bounds__(256)
void gemm_nt(const float* __restrict__ A, int lda, long aoz,
             const float* __restrict__ B, int ldb, long boz,
             const float* __restrict__ bias,
             float* __restrict__ C, int ldc, long coz,
             int K, const float* __restrict__ tptr)
{
    A += (long)blockIdx.z * aoz;
    B += (long)blockIdx.z * boz;
    C += (long)blockIdx.z * coz;
    const float scale = tptr ? (1.0f / (8.0f * tptr[0])) : 1.0f;

    __shared__ float As[16][68];
    __shared__ float Bs[16][68];

    const int tid = threadIdx.x;
    const int i0 = blockIdx.x * 64;
    const int j0 = blockIdx.y * 64;
    const int tx = tid & 15, ty = tid >> 4;
    const int lr = tid >> 2;          // 0..63 row within tile
    const int lc = (tid & 3) << 2;    // 0,4,8,12 k within tile

    float acc[4][4] = {};

    for (int k0 = 0; k0 < K; k0 += 16) {
        float4 av = *reinterpret_cast<const float4*>(A + (long)(i0 + lr) * lda + (k0 + lc));
        float4 bv = *reinterpret_cast<const float4*>(B + (long)(j0 + lr) * ldb + (k0 + lc));
        As[lc + 0][lr] = av.x; As[lc + 1][lr] = av.y; As[lc + 2][lr] = av.z; As[lc + 3][lr] = av.w;
        Bs[lc + 0][lr] = bv.x; Bs[lc + 1][lr] = bv.y; Bs[lc + 2][lr] = bv.z; Bs[lc + 3][lr] = bv.w;
        __syncthreads();
#pragma unroll
        for (int kk = 0; kk < 16; kk++) {
            float4 a = *reinterpret_cast<const float4*>(&As[kk][ty << 2]);
            float4 b = *reinterpret_cast<const float4*>(&Bs[kk][tx << 2]);
            float ar[4] = {a.x, a.y, a.z, a.w};
            float br[4] = {b.x, b.y, b.z, b.w};
#pragma unroll
            for (int p = 0; p < 4; p++)
#pragma unroll
                for (int q = 0; q < 4; q++)
                    acc[p][q] += ar[p] * br[q];
        }
        __syncthreads();
    }

#pragma unroll
    for (int p = 0; p < 4; p++) {
        const int row = i0 + (ty << 2) + p;
        const int col = j0 + (tx << 2);
        float4 o;
        o.x = acc[p][0] * scale; o.y = acc[p][1] * scale;
        o.z = acc[p][2] * scale; o.w = acc[p][3] * scale;
        if (bias) {
            o.x += bias[col + 0]; o.y += bias[col + 1];
            o.z += bias[col + 2]; o.w += bias[col + 3];
        }
        *reinterpret_cast<float4*>(C + (long)row * ldc + col) = o;
    }
}

// ---------------------------------------------------------------------------
// GEMM NN: C[i,j] = sum_k A[i,k]*B[k,j]   (for x = attn @ v, per head)
// ---------------------------------------------------------------------------
__global__ __launch_bounds__(256)
void gemm_nn(const float* __restrict__ A, int lda, long aoz,
             const float* __restrict__ B, int ldb, long boz,
             float* __restrict__ C, int ldc, long coz,
             int K)
{
    A += (long)blockIdx.z * aoz;
    B += (long)blockIdx.z * boz;
    C += (long)blockIdx.z * coz;

    __shared__ float As[16][68];
    __shared__ float Bs[16][68];

    const int tid = threadIdx.x;
    const int i0 = blockIdx.x * 64;
    const int j0 = blockIdx.y * 64;
    const int tx = tid & 15, ty = tid >> 4;
    const int lr = tid >> 2;          // A: 0..63 row
    const int lc = (tid & 3) << 2;    // A: k 0,4,8,12
    const int br = tid >> 4;          // B: 0..15 k-row
    const int bc = (tid & 15) << 2;   // B: 0..60 col

    float acc[4][4] = {};

    for (int k0 = 0; k0 < K; k0 += 16) {
        float4 av = *reinterpret_cast<const float4*>(A + (long)(i0 + lr) * lda + (k0 + lc));
        float4 bv = *reinterpret_cast<const float4*>(B + (long)(k0 + br) * ldb + (j0 + bc));
        As[lc + 0][lr] = av.x; As[lc + 1][lr] = av.y; As[lc + 2][lr] = av.z; As[lc + 3][lr] = av.w;
        *reinterpret_cast<float4*>(&Bs[br][bc]) = bv;
        __syncthreads();
#pragma unroll
        for (int kk = 0; kk < 16; kk++) {
            float4 a = *reinterpret_cast<const float4*>(&As[kk][ty << 2]);
            float4 b = *reinterpret_cast<const float4*>(&Bs[kk][tx << 2]);
            float ar[4] = {a.x, a.y, a.z, a.w};
            float br4[4] = {b.x, b.y, b.z, b.w};
#pragma unroll
            for (int p = 0; p < 4; p++)
#pragma unroll
                for (int q = 0; q < 4; q++)
                    acc[p][q] += ar[p] * br4[q];
        }
        __syncthreads();
    }

#pragma unroll
    for (int p = 0; p < 4; p++) {
        const int row = i0 + (ty << 2) + p;
        const int col = j0 + (tx << 2);
        float4 o;
        o.x = acc[p][0]; o.y = acc[p][1]; o.z = acc[p][2]; o.w = acc[p][3];
        *reinterpret_cast<float4*>(C + (long)row * ldc + col) = o;
    }
}

// ---------------------------------------------------------------------------
// One mean-shift iteration. One block per row n, 256 threads.
// Each thread holds e[h=8][j=8] (m = tid + 256*j) in registers.
// Pass 1: e = exp(scores + L) masked, accumulate per-head Z.
// Pass 2: xyz_new[n] = sum_m (mean_h e/Z_h) * xyz[m]; optionally write attn.
// ---------------------------------------------------------------------------
__global__ __launch_bounds__(256)
void ms_iter(const float* __restrict__ scores,
             const float* __restrict__ xyz_src,
             float* __restrict__ xyz_dst,
             const float* __restrict__ y_hat,
             const int* __restrict__ dmask,
             const float* __restrict__ bwp,
             float* __restrict__ attn_out,
             int write_attn)
{
    const int n = blockIdx.x;
    const int tid = threadIdx.x;
    const int lane = tid & 63;
    const int wave = tid >> 6;

    __shared__ float red[64];

    const float bw = bwp[0];
    const float c2 = 1.0f / (2.0f * bw * bw);

    const float xn = xyz_src[n * 3 + 0];
    const float yn = xyz_src[n * 3 + 1];
    const float zn = xyz_src[n * 3 + 2];
    const float sqn = xn * xn + yn * yn + zn * zn;

    float e[8][8];
    float z[8] = {0.f, 0.f, 0.f, 0.f, 0.f, 0.f, 0.f, 0.f};

#pragma unroll
    for (int j = 0; j < 8; j++) {
        const int m = tid + j * 256;
        const float mx = xyz_src[m * 3 + 0];
        const float my = xyz_src[m * 3 + 1];
        const float mz = xyz_src[m * 3 + 2];
        const float sqm = mx * mx + my * my + mz * mz;
        const float d2 = sqn + sqm - 2.0f * (xn * mx + yn * my + zn * mz);
        const float L = __logf(__expf(-d2 * c2) * y_hat[m] + 1e-9f);
        const bool mk = dmask[n * 2048 + m] > 0;
#pragma unroll
        for (int h = 0; h < 8; h++) {
            const float s = scores[((h << 11) + n) * 2048 + m];
            const float ee = mk ? __expf(s + L) : 0.0f;
            e[h][j] = ee;
            z[h] += ee;
        }
    }

    // block-reduce Z per head
#pragma unroll
    for (int h = 0; h < 8; h++) {
        float v = z[h];
#pragma unroll
        for (int off = 32; off > 0; off >>= 1) v += __shfl_down(v, off, 64);
        if (lane == 0) red[wave * 8 + h] = v;
    }
    __syncthreads();
    if (tid < 8) {
        const float s = red[tid] + red[8 + tid] + red[16 + tid] + red[24 + tid];
        red[32 + tid] = 1.0f / s;
    }
    __syncthreads();
    float invz[8];
#pragma unroll
    for (int h = 0; h < 8; h++) invz[h] = red[32 + h];
    __syncthreads();   // red is reused below

    float ax = 0.f, ay = 0.f, az = 0.f;
#pragma unroll
    for (int j = 0; j < 8; j++) {
        const int m = tid + j * 256;
        float w = 0.f;
#pragma unroll
        for (int h = 0; h < 8; h++) w += e[h][j] * invz[h];
        w *= 0.125f;
        const float mx = xyz_src[m * 3 + 0];
        const float my = xyz_src[m * 3 + 1];
        const float mz = xyz_src[m * 3 + 2];
        ax += w * mx; ay += w * my; az += w * mz;
        if (write_attn) {
#pragma unroll
            for (int h = 0; h < 8; h++)
                attn_out[((h << 11) + n) * 2048 + m] = e[h][j] * invz[h];
        }
    }

    float v3[3] = {ax, ay, az};
#pragma unroll
    for (int c = 0; c < 3; c++) {
        float v = v3[c];
#pragma unroll
        for (int off = 32; off > 0; off >>= 1) v += __shfl_down(v, off, 64);
        if (lane == 0) red[c * 4 + wave] = v;
    }
    __syncthreads();
    if (tid < 3) {
        xyz_dst[n * 3 + tid] = red[tid * 4 + 0] + red[tid * 4 + 1] +
                               red[tid * 4 + 2] + red[tid * 4 + 3];
    }
}

// ---------------------------------------------------------------------------
extern "C" void kernel_launch(void* const* d_in, const int* in_sizes, int n_in,
                              void* d_out, int out_size, void* d_ws, size_t ws_size,
                              hipStream_t stream)
{
    (void)in_sizes; (void)n_in; (void)out_size; (void)ws_size;

    const float* xyz   = (const float*)d_in[0];
    const float* strf  = (const float*)d_in[1];
    // d_in[2] esm_feat: dead code in reference (DCE'd)
    const float* yhat  = (const float*)d_in[3];
    const int*   dmask = (const int*)d_in[4];
    const float* tptr  = (const float*)d_in[5];
    const float* bwptr = (const float*)d_in[6];
    // d_in[7] max_iter = 5 (fixed by setup_inputs; graph capture needs fixed work)
    const float* Wq = (const float*)d_in[8];
    const float* bq = (const float*)d_in[9];
    const float* Wk = (const float*)d_in[10];
    const float* bk = (const float*)d_in[11];
    const float* Wv = (const float*)d_in[12];
    const float* bv = (const float*)d_in[13];
    const float* Wo = (const float*)d_in[14];
    const float* bo = (const float*)d_in[15];
    float* outp = (float*)d_out;

    float* ws = (float*)d_ws;
    const long M1 = 2048L * 512;               // one [N,D] buffer
    float* qb   = ws;                          // [2048,512]
    float* kb   = ws + M1;                     // [2048,512]
    float* vb   = ws + 2 * M1;                 // [2048,512]
    float* xb   = ws + 3 * M1;                 // [2048,512]  (x, head-interleaved)
    float* xyzA = ws + 4 * M1;                 // [2048,3]
    float* xyzB = xyzA + 8192;                 // [2048,3]
    float* sc   = xyzA + 16384;                // [8,2048,2048] scores -> attn (in place)

    dim3 blk(256, 1, 1);

    // q/k/v projections: [2048,512] = strf @ W.T + b
    gemm_nt<<<dim3(32, 8, 1), blk, 0, stream>>>(strf, 512, 0, Wq, 512, 0, bq, qb, 512, 0, 512, nullptr);
    gemm_nt<<<dim3(32, 8, 1), blk, 0, stream>>>(strf, 512, 0, Wk, 512, 0, bk, kb, 512, 0, 512, nullptr);
    gemm_nt<<<dim3(32, 8, 1), blk, 0, stream>>>(strf, 512, 0, Wv, 512, 0, bv, vb, 512, 0, 512, nullptr);

    // scores[h] = (1/(8*t)) * qh @ kh^T  (loop-invariant; fold 1/sqrt(dh)/temp)
    gemm_nt<<<dim3(32, 32, 8), blk, 0, stream>>>(qb, 512, 64, kb, 512, 64, nullptr,
                                                 sc, 2048, 2048L * 2048, 64, tptr);

    // 5 mean-shift iterations; only the last needs attn (for x = attn @ v)
    const float* src = xyz;
    float* dsts[5] = {xyzA, xyzB, xyzA, xyzB, outp};  // last writes xyz_out directly
    for (int it = 0; it < 5; it++) {
        ms_iter<<<dim3(2048), blk, 0, stream>>>(sc, src, dsts[it], yhat, dmask, bwptr,
                                                sc, it == 4 ? 1 : 0);
        src = dsts[it];
    }

    // x[n, h*64+d] = sum_m attn[h,n,m] * v[m, h*64+d]
    gemm_nn<<<dim3(32, 1, 8), blk, 0, stream>>>(sc, 2048, 2048L * 2048,
                                                vb, 512, 64, xb, 512, 64, 2048);

    // out = x @ Wo.T + bo  -> d_out after the 6144-float xyz_out block
    gemm_nt<<<dim3(32, 8, 1), blk, 0, stream>>>(xb, 512, 0, Wo, 512, 0, bo,
                                                outp + 6144, 512, 0, 512, nullptr);
}

// Round 2
// 634.570 us; speedup vs baseline: 1.0797x; 1.0797x over previous
//
#include <hip/hip_runtime.h>

// Problem constants (fixed by setup_inputs): N=2048, D=512, H=8, dh=64, max_iter=5.

typedef __attribute__((ext_vector_type(8))) short bf16x8;
typedef __attribute__((ext_vector_type(4))) float f32x4;

__device__ __forceinline__ unsigned short f2bf(float f) {
    unsigned int u = __float_as_uint(f);
    u += 0x7fff + ((u >> 16) & 1);   // round-to-nearest-even (inputs finite)
    return (unsigned short)(u >> 16);
}

// ---------------------------------------------------------------------------
// GEMM NT: C[i,j] = scale * sum_k A[i,k]*B[j,k] (+ bias[j])
// 64x64 tile per block, 256 threads, 4x4 micro-tile, K-tile 16.
// blockIdx.z offsets pointers by aoz/boz/coz (for per-head batched use).
// scale = 1/(8*t) when tptr != nullptr (scores), else 1.
// ---------------------------------------------------------------------------
__global__ __launch_bounds__(256)
void gemm_nt(const float* __restrict__ A, int lda, long aoz,
             const float* __restrict__ B, int ldb, long boz,
             const float* __restrict__ bias,
             float* __restrict__ C, int ldc, long coz,
             int K, const float* __restrict__ tptr)
{
    A += (long)blockIdx.z * aoz;
    B += (long)blockIdx.z * boz;
    C += (long)blockIdx.z * coz;
    const float scale = tptr ? (1.0f / (8.0f * tptr[0])) : 1.0f;

    __shared__ float As[16][68];
    __shared__ float Bs[16][68];

    const int tid = threadIdx.x;
    const int i0 = blockIdx.x * 64;
    const int j0 = blockIdx.y * 64;
    const int tx = tid & 15, ty = tid >> 4;
    const int lr = tid >> 2;          // 0..63 row within tile
    const int lc = (tid & 3) << 2;    // 0,4,8,12 k within tile

    float acc[4][4] = {};

    for (int k0 = 0; k0 < K; k0 += 16) {
        float4 av = *reinterpret_cast<const float4*>(A + (long)(i0 + lr) * lda + (k0 + lc));
        float4 bv = *reinterpret_cast<const float4*>(B + (long)(j0 + lr) * ldb + (k0 + lc));
        As[lc + 0][lr] = av.x; As[lc + 1][lr] = av.y; As[lc + 2][lr] = av.z; As[lc + 3][lr] = av.w;
        Bs[lc + 0][lr] = bv.x; Bs[lc + 1][lr] = bv.y; Bs[lc + 2][lr] = bv.z; Bs[lc + 3][lr] = bv.w;
        __syncthreads();
#pragma unroll
        for (int kk = 0; kk < 16; kk++) {
            float4 a = *reinterpret_cast<const float4*>(&As[kk][ty << 2]);
            float4 b = *reinterpret_cast<const float4*>(&Bs[kk][tx << 2]);
            float ar[4] = {a.x, a.y, a.z, a.w};
            float br[4] = {b.x, b.y, b.z, b.w};
#pragma unroll
            for (int p = 0; p < 4; p++)
#pragma unroll
                for (int q = 0; q < 4; q++)
                    acc[p][q] += ar[p] * br[q];
        }
        __syncthreads();
    }

#pragma unroll
    for (int p = 0; p < 4; p++) {
        const int row = i0 + (ty << 2) + p;
        const int col = j0 + (tx << 2);
        float4 o;
        o.x = acc[p][0] * scale; o.y = acc[p][1] * scale;
        o.z = acc[p][2] * scale; o.w = acc[p][3] * scale;
        if (bias) {
            o.x += bias[col + 0]; o.y += bias[col + 1];
            o.z += bias[col + 2]; o.w += bias[col + 3];
        }
        *reinterpret_cast<float4*>(C + (long)row * ldc + col) = o;
    }
}

// ---------------------------------------------------------------------------
// dmask int32 [2048*2048] -> uint8 (1 if >0). 4 elements/thread.
// ---------------------------------------------------------------------------
__global__ __launch_bounds__(256)
void mask_to_byte(const int* __restrict__ dm, unsigned char* __restrict__ mb)
{
    const int i = blockIdx.x * 256 + threadIdx.x;
    int4 v = reinterpret_cast<const int4*>(dm)[i];
    uchar4 o;
    o.x = v.x > 0; o.y = v.y > 0; o.z = v.z > 0; o.w = v.w > 0;
    reinterpret_cast<uchar4*>(mb)[i] = o;
}

// ---------------------------------------------------------------------------
// vT[c][m] = bf16(v[m][c]), c = h*64+d.  64x64 LDS tile transpose.
// grid (32, 8), 256 threads.
// ---------------------------------------------------------------------------
__global__ __launch_bounds__(256)
void v_transpose(const float* __restrict__ v, unsigned short* __restrict__ vT)
{
    __shared__ float ls[64][68];
    const int m0 = blockIdx.x * 64;
    const int c0 = blockIdx.y * 64;
    const int tid = threadIdx.x;
    const int r  = tid >> 4;
    const int c4 = (tid & 15) * 4;
#pragma unroll
    for (int i = 0; i < 4; i++) {
        float4 x = *reinterpret_cast<const float4*>(v + (long)(m0 + r + i * 16) * 512 + c0 + c4);
        *reinterpret_cast<float4*>(&ls[r + i * 16][c4]) = x;
    }
    __syncthreads();
    const int mcol4 = (tid & 15) * 4;
#pragma unroll
    for (int i = 0; i < 4; i++) {
        const int crow = r + i * 16;
        ushort4 o;
        o.x = f2bf(ls[mcol4 + 0][crow]);
        o.y = f2bf(ls[mcol4 + 1][crow]);
        o.z = f2bf(ls[mcol4 + 2][crow]);
        o.w = f2bf(ls[mcol4 + 3][crow]);
        *reinterpret_cast<ushort4*>(vT + (long)(c0 + crow) * 2048 + m0 + mcol4) = o;
    }
}

// ---------------------------------------------------------------------------
// One mean-shift iteration. One block per row n, 256 threads.
// Each thread holds e[h=8][j=8] (m = tid + 256*j) in registers.
// Pass 1: e = exp(scores + L) masked, accumulate per-head Z.
// Pass 2: xyz_new[n] = sum_m (mean_h e/Z_h) * xyz[m]; optionally write
//         normalized attn IN PLACE over scores (block n only touches rows n).
// ---------------------------------------------------------------------------
__global__ __launch_bounds__(256)
void ms_iter(const float* __restrict__ scores,
             const float* __restrict__ xyz_src,
             float* __restrict__ xyz_dst,
             const float* __restrict__ y_hat,
             const unsigned char* __restrict__ mb,
             const float* __restrict__ bwp,
             float* __restrict__ attn_out,
             int write_attn)
{
    const int n = blockIdx.x;
    const int tid = threadIdx.x;
    const int lane = tid & 63;
    const int wave = tid >> 6;

    __shared__ float red[64];

    const float bw = bwp[0];
    const float c2 = 1.0f / (2.0f * bw * bw);

    const float xn = xyz_src[n * 3 + 0];
    const float yn = xyz_src[n * 3 + 1];
    const float zn = xyz_src[n * 3 + 2];
    const float sqn = xn * xn + yn * yn + zn * zn;

    float e[8][8];
    float z[8] = {0.f, 0.f, 0.f, 0.f, 0.f, 0.f, 0.f, 0.f};

#pragma unroll
    for (int j = 0; j < 8; j++) {
        const int m = tid + j * 256;
        const float mx = xyz_src[m * 3 + 0];
        const float my = xyz_src[m * 3 + 1];
        const float mz = xyz_src[m * 3 + 2];
        const float sqm = mx * mx + my * my + mz * mz;
        const float d2 = sqn + sqm - 2.0f * (xn * mx + yn * my + zn * mz);
        const float L = __logf(__expf(-d2 * c2) * y_hat[m] + 1e-9f);
        const bool mk = mb[n * 2048 + m] != 0;
#pragma unroll
        for (int h = 0; h < 8; h++) {
            const float s = scores[((h << 11) + n) * 2048 + m];
            const float ee = mk ? __expf(s + L) : 0.0f;
            e[h][j] = ee;
            z[h] += ee;
        }
    }

    // block-reduce Z per head
#pragma unroll
    for (int h = 0; h < 8; h++) {
        float v = z[h];
#pragma unroll
        for (int off = 32; off > 0; off >>= 1) v += __shfl_down(v, off, 64);
        if (lane == 0) red[wave * 8 + h] = v;
    }
    __syncthreads();
    if (tid < 8) {
        const float s = red[tid] + red[8 + tid] + red[16 + tid] + red[24 + tid];
        red[32 + tid] = 1.0f / s;
    }
    __syncthreads();
    float invz[8];
#pragma unroll
    for (int h = 0; h < 8; h++) invz[h] = red[32 + h];
    __syncthreads();   // red is reused below

    float ax = 0.f, ay = 0.f, az = 0.f;
#pragma unroll
    for (int j = 0; j < 8; j++) {
        const int m = tid + j * 256;
        float w = 0.f;
#pragma unroll
        for (int h = 0; h < 8; h++) w += e[h][j] * invz[h];
        w *= 0.125f;
        const float mx = xyz_src[m * 3 + 0];
        const float my = xyz_src[m * 3 + 1];
        const float mz = xyz_src[m * 3 + 2];
        ax += w * mx; ay += w * my; az += w * mz;
        if (write_attn) {
#pragma unroll
            for (int h = 0; h < 8; h++)
                attn_out[((h << 11) + n) * 2048 + m] = e[h][j] * invz[h];
        }
    }

    float v3[3] = {ax, ay, az};
#pragma unroll
    for (int c = 0; c < 3; c++) {
        float v = v3[c];
#pragma unroll
        for (int off = 32; off > 0; off >>= 1) v += __shfl_down(v, off, 64);
        if (lane == 0) red[c * 4 + wave] = v;
    }
    __syncthreads();
    if (tid < 3) {
        xyz_dst[n * 3 + tid] = red[tid * 4 + 0] + red[tid * 4 + 1] +
                               red[tid * 4 + 2] + red[tid * 4 + 3];
    }
}

// ---------------------------------------------------------------------------
// attn @ v via MFMA bf16.  xb[n][h*64+d] += sum_m attn[h][n][m] * vT[h*64+d][m]
// grid (32 row-tiles, 4 K-splits, 8 heads), 256 threads = 4 waves.
// Wave w: rows n0 = bx*64 + w*16 .. +16, all 64 d (4 MFMA d-tiles), K-chunk 512.
// A fragment loaded fp32 -> bf16 convert; B fragment straight bf16 from vT.
// fp32 atomicAdd into pre-zeroed xb.
// ---------------------------------------------------------------------------
__global__ __launch_bounds__(256)
void av_mfma(const float* __restrict__ attn,          // [8][2048][2048] fp32 (normalized)
             const unsigned short* __restrict__ vT,   // [512][2048] bf16
             float* __restrict__ xb)                  // [2048][512] fp32, zeroed
{
    const int h  = blockIdx.z;
    const int s  = blockIdx.y;
    const int bx = blockIdx.x;
    const int wv = threadIdx.x >> 6;
    const int lane = threadIdx.x & 63;
    const int n0 = bx * 64 + wv * 16;
    const int kc = s * 512;

    const int mrow = lane & 15;          // A row (n) / B col (d) within tile
    const int koct = (lane >> 4) * 8;    // K octet base

    const float* Ab = attn + ((long)h * 2048 + n0 + mrow) * 2048;
    const unsigned short* Bb = vT + ((long)h * 64 + mrow) * 2048;

    f32x4 acc[4] = {};

    for (int k0 = kc; k0 < kc + 512; k0 += 32) {
        float4 a0 = *reinterpret_cast<const float4*>(Ab + k0 + koct);
        float4 a1 = *reinterpret_cast<const float4*>(Ab + k0 + koct + 4);
        union { bf16x8 v; unsigned short u[8]; } af;
        af.u[0] = f2bf(a0.x); af.u[1] = f2bf(a0.y);
        af.u[2] = f2bf(a0.z); af.u[3] = f2bf(a0.w);
        af.u[4] = f2bf(a1.x); af.u[5] = f2bf(a1.y);
        af.u[6] = f2bf(a1.z); af.u[7] = f2bf(a1.w);
#pragma unroll
        for (int t = 0; t < 4; t++) {
            bf16x8 bfv = *reinterpret_cast<const bf16x8*>(Bb + (long)(t * 16) * 2048 + k0 + koct);
            acc[t] = __builtin_amdgcn_mfma_f32_16x16x32_bf16(af.v, bfv, acc[t], 0, 0, 0);
        }
    }

    // C/D layout: col = lane&15, row = (lane>>4)*4 + reg
    const int rbase = n0 + (lane >> 4) * 4;
    const int dcol = lane & 15;
#pragma unroll
    for (int t = 0; t < 4; t++)
#pragma unroll
        for (int r = 0; r < 4; r++)
            atomicAdd(&xb[(long)(rbase + r) * 512 + h * 64 + t * 16 + dcol], acc[t][r]);
}

// ---------------------------------------------------------------------------
extern "C" void kernel_launch(void* const* d_in, const int* in_sizes, int n_in,
                              void* d_out, int out_size, void* d_ws, size_t ws_size,
                              hipStream_t stream)
{
    (void)in_sizes; (void)n_in; (void)out_size; (void)ws_size;

    const float* xyz   = (const float*)d_in[0];
    const float* strf  = (const float*)d_in[1];
    // d_in[2] esm_feat: dead code in reference (DCE'd)
    const float* yhat  = (const float*)d_in[3];
    const int*   dmask = (const int*)d_in[4];
    const float* tptr  = (const float*)d_in[5];
    const float* bwptr = (const float*)d_in[6];
    // d_in[7] max_iter = 5 (fixed by setup_inputs)
    const float* Wq = (const float*)d_in[8];
    const float* bq = (const float*)d_in[9];
    const float* Wk = (const float*)d_in[10];
    const float* bk = (const float*)d_in[11];
    const float* Wv = (const float*)d_in[12];
    const float* bv = (const float*)d_in[13];
    const float* Wo = (const float*)d_in[14];
    const float* bo = (const float*)d_in[15];
    float* outp = (float*)d_out;

    float* ws = (float*)d_ws;
    const long M1 = 2048L * 512;               // one [N,D] fp32 buffer (4 MB)
    float* qb   = ws;                          // [2048,512]; dead after scores -> mb alias
    float* kb   = ws + M1;                     // [2048,512]; dead after scores -> vT alias
    float* vb   = ws + 2 * M1;                 // [2048,512]; dead after v_transpose
    float* xb   = ws + 3 * M1;                 // [2048,512]  x (head-interleaved), atomic acc
    float* xyzA = ws + 4 * M1;                 // [2048,3]
    float* xyzB = xyzA + 8192;                 // [2048,3]
    float* sc   = xyzA + 16384;                // [8,2048,2048] scores -> attn (in place)
    unsigned char*  mbyte = (unsigned char*)qb;   // [2048*2048] u8 (4 MB) over dead qb
    unsigned short* vT    = (unsigned short*)kb;  // [512][2048] bf16 (2 MB) over dead kb

    dim3 blk(256, 1, 1);

    // q/k/v projections: [2048,512] = strf @ W.T + b
    gemm_nt<<<dim3(32, 8, 1), blk, 0, stream>>>(strf, 512, 0, Wq, 512, 0, bq, qb, 512, 0, 512, nullptr);
    gemm_nt<<<dim3(32, 8, 1), blk, 0, stream>>>(strf, 512, 0, Wk, 512, 0, bk, kb, 512, 0, 512, nullptr);
    gemm_nt<<<dim3(32, 8, 1), blk, 0, stream>>>(strf, 512, 0, Wv, 512, 0, bv, vb, 512, 0, 512, nullptr);

    // scores[h] = (1/(8*t)) * qh @ kh^T  (loop-invariant; folds 1/sqrt(dh)/temp)
    gemm_nt<<<dim3(32, 32, 8), blk, 0, stream>>>(qb, 512, 64, kb, 512, 64, nullptr,
                                                 sc, 2048, 2048L * 2048, 64, tptr);

    // prep (after scores GEMM frees qb/kb): byte mask + bf16 v-transpose
    mask_to_byte<<<dim3(4096), blk, 0, stream>>>(dmask, mbyte);
    v_transpose<<<dim3(32, 8, 1), blk, 0, stream>>>(vb, vT);

    // 5 mean-shift iterations; only the last needs normalized attn
    const float* src = xyz;
    float* dsts[5] = {xyzA, xyzB, xyzA, xyzB, outp};  // last writes xyz_out directly
    for (int it = 0; it < 5; it++) {
        ms_iter<<<dim3(2048), blk, 0, stream>>>(sc, src, dsts[it], yhat, mbyte, bwptr,
                                                sc, it == 4 ? 1 : 0);
        src = dsts[it];
    }

    // x = attn @ v  (MFMA, split-K atomic accumulate into zeroed xb)
    hipMemsetAsync(xb, 0, M1 * sizeof(float), stream);
    av_mfma<<<dim3(32, 4, 8), blk, 0, stream>>>(sc, vT, xb);

    // out = x @ Wo.T + bo  -> d_out after the 6144-float xyz_out block
    gemm_nt<<<dim3(32, 8, 1), blk, 0, stream>>>(xb, 512, 0, Wo, 512, 0, bo,
                                                outp + 6144, 512, 0, 512, nullptr);
}

// Round 3
// 397.330 us; speedup vs baseline: 1.7244x; 1.5971x over previous
//
#include <hip/hip_runtime.h>

// Problem constants (fixed by setup_inputs): N=2048, D=512, H=8, dh=64, max_iter=5.
// Key identity: exp(s/t + log(kern*yw+eps)) = exp(s/t) * (kern*yw+eps).
// E[h,n,m] = mask ? exp(s/(8t)) : 0 is loop-invariant -> computed once (bf16, 67MB,
// fits 256MB L3), per-iteration work is just the kernel term g[n,m] = kern*yw+eps.

typedef __attribute__((ext_vector_type(8))) short bf16x8;
typedef __attribute__((ext_vector_type(4))) float f32x4;

__device__ __forceinline__ unsigned short f2bf(float f) {
    unsigned int u = __float_as_uint(f);
    u += 0x7fff + ((u >> 16) & 1);   // RNE (inputs finite)
    return (unsigned short)(u >> 16);
}
__device__ __forceinline__ float bf2f(unsigned short u) {
    return __uint_as_float((unsigned int)u << 16);
}

union EU { bf16x8 v; unsigned short u[8]; };

// ---------------------------------------------------------------------------
// Fused q/k/v projection: z=0 -> q (bf16), z=1 -> k (bf16), z=2 -> v (fp32).
// C[i,j] = sum_k A[i,k]*W[j,k] + b[j].  64x64 tile, 256 thr, 4x4 micro, K=512.
// ---------------------------------------------------------------------------
__global__ __launch_bounds__(256)
void qkv_gemm(const float* __restrict__ A,
              const float* __restrict__ Wq, const float* __restrict__ bq,
              const float* __restrict__ Wk, const float* __restrict__ bk,
              const float* __restrict__ Wv, const float* __restrict__ bv,
              unsigned short* __restrict__ qh, unsigned short* __restrict__ kh,
              float* __restrict__ vb)
{
    const float* B; const float* bias;
    if (blockIdx.z == 0)      { B = Wq; bias = bq; }
    else if (blockIdx.z == 1) { B = Wk; bias = bk; }
    else                      { B = Wv; bias = bv; }

    __shared__ float As[16][68];
    __shared__ float Bs[16][68];

    const int tid = threadIdx.x;
    const int i0 = blockIdx.x * 64;
    const int j0 = blockIdx.y * 64;
    const int tx = tid & 15, ty = tid >> 4;
    const int lr = tid >> 2;
    const int lc = (tid & 3) << 2;

    float acc[4][4] = {};

    for (int k0 = 0; k0 < 512; k0 += 16) {
        float4 av = *reinterpret_cast<const float4*>(A + (long)(i0 + lr) * 512 + (k0 + lc));
        float4 bv4 = *reinterpret_cast<const float4*>(B + (long)(j0 + lr) * 512 + (k0 + lc));
        As[lc + 0][lr] = av.x; As[lc + 1][lr] = av.y; As[lc + 2][lr] = av.z; As[lc + 3][lr] = av.w;
        Bs[lc + 0][lr] = bv4.x; Bs[lc + 1][lr] = bv4.y; Bs[lc + 2][lr] = bv4.z; Bs[lc + 3][lr] = bv4.w;
        __syncthreads();
#pragma unroll
        for (int kk = 0; kk < 16; kk++) {
            float4 a = *reinterpret_cast<const float4*>(&As[kk][ty << 2]);
            float4 b = *reinterpret_cast<const float4*>(&Bs[kk][tx << 2]);
            float ar[4] = {a.x, a.y, a.z, a.w};
            float br[4] = {b.x, b.y, b.z, b.w};
#pragma unroll
            for (int p = 0; p < 4; p++)
#pragma unroll
                for (int q = 0; q < 4; q++)
                    acc[p][q] += ar[p] * br[q];
        }
        __syncthreads();
    }

#pragma unroll
    for (int p = 0; p < 4; p++) {
        const int row = i0 + (ty << 2) + p;
        const int col = j0 + (tx << 2);
        float o[4];
#pragma unroll
        for (int q = 0; q < 4; q++) o[q] = acc[p][q] + bias[col + q];
        if (blockIdx.z == 2) {
            float4 f; f.x = o[0]; f.y = o[1]; f.z = o[2]; f.w = o[3];
            *reinterpret_cast<float4*>(vb + (long)row * 512 + col) = f;
        } else {
            ushort4 us;
            us.x = f2bf(o[0]); us.y = f2bf(o[1]); us.z = f2bf(o[2]); us.w = f2bf(o[3]);
            unsigned short* dst = (blockIdx.z == 0) ? qh : kh;
            *reinterpret_cast<ushort4*>(dst + (long)row * 512 + col) = us;
        }
    }
}

// ---------------------------------------------------------------------------
// vT[c][m] = bf16(v[m][c]), c = h*64+d.  64x64 LDS tile transpose. grid (32,8).
// ---------------------------------------------------------------------------
__global__ __launch_bounds__(256)
void v_transpose(const float* __restrict__ v, unsigned short* __restrict__ vT)
{
    __shared__ float ls[64][68];
    const int m0 = blockIdx.x * 64;
    const int c0 = blockIdx.y * 64;
    const int tid = threadIdx.x;
    const int r  = tid >> 4;
    const int c4 = (tid & 15) * 4;
#pragma unroll
    for (int i = 0; i < 4; i++) {
        float4 x = *reinterpret_cast<const float4*>(v + (long)(m0 + r + i * 16) * 512 + c0 + c4);
        *reinterpret_cast<float4*>(&ls[r + i * 16][c4]) = x;
    }
    __syncthreads();
    const int mcol4 = (tid & 15) * 4;
#pragma unroll
    for (int i = 0; i < 4; i++) {
        const int crow = r + i * 16;
        ushort4 o;
        o.x = f2bf(ls[mcol4 + 0][crow]);
        o.y = f2bf(ls[mcol4 + 1][crow]);
        o.z = f2bf(ls[mcol4 + 2][crow]);
        o.w = f2bf(ls[mcol4 + 3][crow]);
        *reinterpret_cast<ushort4*>(vT + (long)(c0 + crow) * 2048 + m0 + mcol4) = o;
    }
}

// ---------------------------------------------------------------------------
// E[h,n,m] = mask ? bf16(exp(scale * q_h[n]·k_h[m])) : 0, via bf16 MFMA.
// grid (32 m-tiles, 32 n-tiles, 8 heads); wave wv does rows n0+wv*16..+16.
// LDS round-trip for coalesced bf16x8 stores.
// ---------------------------------------------------------------------------
__global__ __launch_bounds__(256)
void scores_mfma(const unsigned short* __restrict__ qh,
                 const unsigned short* __restrict__ kh,
                 const int* __restrict__ dmask,
                 const float* __restrict__ tptr,
                 unsigned short* __restrict__ Ebf)
{
    const int h  = blockIdx.z;
    const int m0 = blockIdx.x * 64;
    const int n0 = blockIdx.y * 64;
    const int tid = threadIdx.x;
    const int wv = tid >> 6;
    const int lane = tid & 63;
    const float scale = 1.0f / (8.0f * tptr[0]);

    const int row  = lane & 15;
    const int koct = (lane >> 4) * 8;
    const unsigned short* Aq = qh + (long)(n0 + wv * 16 + row) * 512 + h * 64;
    const unsigned short* Bk = kh + (long)(m0 + row) * 512 + h * 64;

    f32x4 acc[4] = {};
#pragma unroll
    for (int k0 = 0; k0 < 64; k0 += 32) {
        bf16x8 a = *reinterpret_cast<const bf16x8*>(Aq + k0 + koct);
#pragma unroll
        for (int t = 0; t < 4; t++) {
            bf16x8 b = *reinterpret_cast<const bf16x8*>(Bk + (long)(t * 16) * 512 + k0 + koct);
            acc[t] = __builtin_amdgcn_mfma_f32_16x16x32_bf16(a, b, acc[t], 0, 0, 0);
        }
    }

    __shared__ float ls[64][68];
    const int lrb = wv * 16 + (lane >> 4) * 4;   // C/D: row=(lane>>4)*4+r, col=lane&15
    const int lcb = lane & 15;
#pragma unroll
    for (int t = 0; t < 4; t++)
#pragma unroll
        for (int r = 0; r < 4; r++)
            ls[lrb + r][t * 16 + lcb] = acc[t][r];
    __syncthreads();

    const int r2 = tid >> 2;
    const int c2 = (tid & 3) * 16;
    const int gn = n0 + r2;
    const int* mp = dmask + (long)gn * 2048 + m0 + c2;
    int4 mk0 = reinterpret_cast<const int4*>(mp)[0];
    int4 mk1 = reinterpret_cast<const int4*>(mp)[1];
    int4 mk2 = reinterpret_cast<const int4*>(mp)[2];
    int4 mk3 = reinterpret_cast<const int4*>(mp)[3];
    int mk[16] = {mk0.x, mk0.y, mk0.z, mk0.w, mk1.x, mk1.y, mk1.z, mk1.w,
                  mk2.x, mk2.y, mk2.z, mk2.w, mk3.x, mk3.y, mk3.z, mk3.w};
    float4 s0 = *reinterpret_cast<const float4*>(&ls[r2][c2 + 0]);
    float4 s1 = *reinterpret_cast<const float4*>(&ls[r2][c2 + 4]);
    float4 s2 = *reinterpret_cast<const float4*>(&ls[r2][c2 + 8]);
    float4 s3 = *reinterpret_cast<const float4*>(&ls[r2][c2 + 12]);
    float sv[16] = {s0.x, s0.y, s0.z, s0.w, s1.x, s1.y, s1.z, s1.w,
                    s2.x, s2.y, s2.z, s2.w, s3.x, s3.y, s3.z, s3.w};
    EU o0, o1;
#pragma unroll
    for (int j = 0; j < 8; j++)
        o0.u[j] = (mk[j] > 0) ? f2bf(__expf(sv[j] * scale)) : (unsigned short)0;
#pragma unroll
    for (int j = 0; j < 8; j++)
        o1.u[j] = (mk[8 + j] > 0) ? f2bf(__expf(sv[8 + j] * scale)) : (unsigned short)0;
    unsigned short* ep = Ebf + ((long)h * 2048 + gn) * 2048 + m0 + c2;
    *reinterpret_cast<bf16x8*>(ep)     = o0.v;
    *reinterpret_cast<bf16x8*>(ep + 8) = o1.v;
}

// ---------------------------------------------------------------------------
// One mean-shift iteration. One block per row n, 256 threads; thread owns
// m = tid*8 .. +8 (contiguous -> bf16x8 loads). E bf16 stays in 32 VGPRs.
// Pass 1: g[j] = kern*yw+eps; z[h] = sum E*g. Pass 2: xyz update; last iter
// writes bf16 attn = E*g*invz IN PLACE over E (block n owns rows n).
// ---------------------------------------------------------------------------
__global__ __launch_bounds__(256)
void ms_iter(const unsigned short* __restrict__ Ebf,
             const float* __restrict__ xyz_src,
             float* __restrict__ xyz_dst,
             const float* __restrict__ y_hat,
             const float* __restrict__ bwp,
             unsigned short* __restrict__ attn_out,
             int write_attn)
{
    const int n = blockIdx.x;
    const int tid = threadIdx.x;
    const int lane = tid & 63;
    const int wave = tid >> 6;
    const int m0 = tid * 8;

    __shared__ float red[64];

    const float bw = bwp[0];
    const float c2k = 1.0f / (2.0f * bw * bw);

    const float xn = xyz_src[n * 3 + 0];
    const float yn = xyz_src[n * 3 + 1];
    const float zn = xyz_src[n * 3 + 2];
    const float sqn = xn * xn + yn * yn + zn * zn;

    float mx[8], my[8], mz[8];
    {
        const float4* xp = reinterpret_cast<const float4*>(xyz_src + (long)m0 * 3);
        float4 a = xp[0], b = xp[1], c = xp[2], d = xp[3], e = xp[4], f = xp[5];
        mx[0]=a.x; my[0]=a.y; mz[0]=a.z;  mx[1]=a.w; my[1]=b.x; mz[1]=b.y;
        mx[2]=b.z; my[2]=b.w; mz[2]=c.x;  mx[3]=c.y; my[3]=c.z; mz[3]=c.w;
        mx[4]=d.x; my[4]=d.y; mz[4]=d.z;  mx[5]=d.w; my[5]=e.x; mz[5]=e.y;
        mx[6]=e.z; my[6]=e.w; mz[6]=f.x;  mx[7]=f.y; my[7]=f.z; mz[7]=f.w;
    }
    float4 yh0 = *reinterpret_cast<const float4*>(y_hat + m0);
    float4 yh1 = *reinterpret_cast<const float4*>(y_hat + m0 + 4);
    float yh[8] = {yh0.x, yh0.y, yh0.z, yh0.w, yh1.x, yh1.y, yh1.z, yh1.w};

    float g[8];
#pragma unroll
    for (int j = 0; j < 8; j++) {
        const float d2 = sqn + (mx[j]*mx[j] + my[j]*my[j] + mz[j]*mz[j])
                       - 2.0f * (xn*mx[j] + yn*my[j] + zn*mz[j]);
        g[j] = __expf(-d2 * c2k) * yh[j] + 1e-9f;
    }

    EU E[8];
    float z[8];
#pragma unroll
    for (int h = 0; h < 8; h++) {
        E[h].v = *reinterpret_cast<const bf16x8*>(Ebf + ((long)h * 2048 + n) * 2048 + m0);
        float zz = 0.f;
#pragma unroll
        for (int j = 0; j < 8; j++) zz += bf2f(E[h].u[j]) * g[j];
        z[h] = zz;
    }

    // block-reduce z per head
#pragma unroll
    for (int h = 0; h < 8; h++) {
        float v = z[h];
#pragma unroll
        for (int off = 32; off > 0; off >>= 1) v += __shfl_down(v, off, 64);
        if (lane == 0) red[wave * 8 + h] = v;
    }
    __syncthreads();
    if (tid < 8) {
        const float s = red[tid] + red[8 + tid] + red[16 + tid] + red[24 + tid];
        red[32 + tid] = 1.0f / s;
    }
    __syncthreads();
    float invz[8];
#pragma unroll
    for (int h = 0; h < 8; h++) invz[h] = red[32 + h];
    __syncthreads();   // red reused below

    float ax = 0.f, ay = 0.f, az = 0.f;
#pragma unroll
    for (int j = 0; j < 8; j++) {
        float w = 0.f;
#pragma unroll
        for (int h = 0; h < 8; h++) w += bf2f(E[h].u[j]) * invz[h];
        w *= 0.125f * g[j];
        ax += w * mx[j]; ay += w * my[j]; az += w * mz[j];
    }
    if (write_attn) {
#pragma unroll
        for (int h = 0; h < 8; h++) {
            EU o;
#pragma unroll
            for (int j = 0; j < 8; j++)
                o.u[j] = f2bf(bf2f(E[h].u[j]) * g[j] * invz[h]);
            *reinterpret_cast<bf16x8*>(attn_out + ((long)h * 2048 + n) * 2048 + m0) = o.v;
        }
    }

    float v3[3] = {ax, ay, az};
#pragma unroll
    for (int c = 0; c < 3; c++) {
        float v = v3[c];
#pragma unroll
        for (int off = 32; off > 0; off >>= 1) v += __shfl_down(v, off, 64);
        if (lane == 0) red[c * 4 + wave] = v;
    }
    __syncthreads();
    if (tid < 3) {
        xyz_dst[n * 3 + tid] = red[tid * 4 + 0] + red[tid * 4 + 1] +
                               red[tid * 4 + 2] + red[tid * 4 + 3];
    }
}

// ---------------------------------------------------------------------------
// x = attn @ v via MFMA bf16 (both operands bf16 now).
// grid (32 row-tiles, 4 K-splits, 8 heads); fp32 atomicAdd into zeroed xb.
// ---------------------------------------------------------------------------
__global__ __launch_bounds__(256)
void av_mfma(const unsigned short* __restrict__ attn,  // [8][2048][2048] bf16
             const unsigned short* __restrict__ vT,    // [512][2048] bf16
             float* __restrict__ xb)                   // [2048][512] fp32, zeroed
{
    const int h  = blockIdx.z;
    const int s  = blockIdx.y;
    const int bx = blockIdx.x;
    const int wv = threadIdx.x >> 6;
    const int lane = threadIdx.x & 63;
    const int n0 = bx * 64 + wv * 16;
    const int kc = s * 512;

    const int mrow = lane & 15;
    const int koct = (lane >> 4) * 8;

    const unsigned short* Ab = attn + ((long)h * 2048 + n0 + mrow) * 2048;
    const unsigned short* Bb = vT + ((long)h * 64 + mrow) * 2048;

    f32x4 acc[4] = {};
    for (int k0 = kc; k0 < kc + 512; k0 += 32) {
        bf16x8 a = *reinterpret_cast<const bf16x8*>(Ab + k0 + koct);
#pragma unroll
        for (int t = 0; t < 4; t++) {
            bf16x8 b = *reinterpret_cast<const bf16x8*>(Bb + (long)(t * 16) * 2048 + k0 + koct);
            acc[t] = __builtin_amdgcn_mfma_f32_16x16x32_bf16(a, b, acc[t], 0, 0, 0);
        }
    }

    const int rbase = n0 + (lane >> 4) * 4;
    const int dcol = lane & 15;
#pragma unroll
    for (int t = 0; t < 4; t++)
#pragma unroll
        for (int r = 0; r < 4; r++)
            atomicAdd(&xb[(long)(rbase + r) * 512 + h * 64 + t * 16 + dcol], acc[t][r]);
}

// ---------------------------------------------------------------------------
// GEMM NT fp32 (out projection): C = A @ W.T + b
// ---------------------------------------------------------------------------
__global__ __launch_bounds__(256)
void gemm_nt(const float* __restrict__ A,
             const float* __restrict__ B,
             const float* __restrict__ bias,
             float* __restrict__ C)
{
    __shared__ float As[16][68];
    __shared__ float Bs[16][68];

    const int tid = threadIdx.x;
    const int i0 = blockIdx.x * 64;
    const int j0 = blockIdx.y * 64;
    const int tx = tid & 15, ty = tid >> 4;
    const int lr = tid >> 2;
    const int lc = (tid & 3) << 2;

    float acc[4][4] = {};

    for (int k0 = 0; k0 < 512; k0 += 16) {
        float4 av = *reinterpret_cast<const float4*>(A + (long)(i0 + lr) * 512 + (k0 + lc));
        float4 bv = *reinterpret_cast<const float4*>(B + (long)(j0 + lr) * 512 + (k0 + lc));
        As[lc + 0][lr] = av.x; As[lc + 1][lr] = av.y; As[lc + 2][lr] = av.z; As[lc + 3][lr] = av.w;
        Bs[lc + 0][lr] = bv.x; Bs[lc + 1][lr] = bv.y; Bs[lc + 2][lr] = bv.z; Bs[lc + 3][lr] = bv.w;
        __syncthreads();
#pragma unroll
        for (int kk = 0; kk < 16; kk++) {
            float4 a = *reinterpret_cast<const float4*>(&As[kk][ty << 2]);
            float4 b = *reinterpret_cast<const float4*>(&Bs[kk][tx << 2]);
            float ar[4] = {a.x, a.y, a.z, a.w};
            float br[4] = {b.x, b.y, b.z, b.w};
#pragma unroll
            for (int p = 0; p < 4; p++)
#pragma unroll
                for (int q = 0; q < 4; q++)
                    acc[p][q] += ar[p] * br[q];
        }
        __syncthreads();
    }

#pragma unroll
    for (int p = 0; p < 4; p++) {
        const int row = i0 + (ty << 2) + p;
        const int col = j0 + (tx << 2);
        float4 o;
        o.x = acc[p][0] + bias[col + 0];
        o.y = acc[p][1] + bias[col + 1];
        o.z = acc[p][2] + bias[col + 2];
        o.w = acc[p][3] + bias[col + 3];
        *reinterpret_cast<float4*>(C + (long)row * 512 + col) = o;
    }
}

// ---------------------------------------------------------------------------
extern "C" void kernel_launch(void* const* d_in, const int* in_sizes, int n_in,
                              void* d_out, int out_size, void* d_ws, size_t ws_size,
                              hipStream_t stream)
{
    (void)in_sizes; (void)n_in; (void)out_size; (void)ws_size;

    const float* xyz   = (const float*)d_in[0];
    const float* strf  = (const float*)d_in[1];
    // d_in[2] esm_feat: dead code (DCE'd in reference)
    const float* yhat  = (const float*)d_in[3];
    const int*   dmask = (const int*)d_in[4];
    const float* tptr  = (const float*)d_in[5];
    const float* bwptr = (const float*)d_in[6];
    // d_in[7] max_iter = 5 (fixed)
    const float* Wq = (const float*)d_in[8];
    const float* bq = (const float*)d_in[9];
    const float* Wk = (const float*)d_in[10];
    const float* bk = (const float*)d_in[11];
    const float* Wv = (const float*)d_in[12];
    const float* bv = (const float*)d_in[13];
    const float* Wo = (const float*)d_in[14];
    const float* bo = (const float*)d_in[15];
    float* outp = (float*)d_out;

    char* wsb = (char*)d_ws;
    float* xb  = (float*)(wsb);                           // [2048,512] fp32 (4 MB)
    float* vb  = (float*)(wsb + (4L << 20));              // [2048,512] fp32 (4 MB)
    float* xyzA = (float*)(wsb + (8L << 20));             // [2048,3]
    float* xyzB = xyzA + 8192;
    unsigned short* qh  = (unsigned short*)(wsb + (9L << 20));   // [2048,512] bf16 (2 MB)
    unsigned short* kh  = (unsigned short*)(wsb + (11L << 20));  // [2048,512] bf16 (2 MB)
    unsigned short* vT  = (unsigned short*)(wsb + (13L << 20));  // [512,2048] bf16 (2 MB)
    unsigned short* Ebf = (unsigned short*)(wsb + (16L << 20));  // [8,2048,2048] bf16 (64 MB)

    dim3 blk(256, 1, 1);

    // fused q/k/v projections (q,k -> bf16; v -> fp32)
    qkv_gemm<<<dim3(32, 8, 3), blk, 0, stream>>>(strf, Wq, bq, Wk, bk, Wv, bv, qh, kh, vb);
    v_transpose<<<dim3(32, 8, 1), blk, 0, stream>>>(vb, vT);

    // E = mask ? exp(q·k/(8t)) : 0, bf16 (loop-invariant, mask fused)
    scores_mfma<<<dim3(32, 32, 8), blk, 0, stream>>>(qh, kh, dmask, tptr, Ebf);

    // 5 mean-shift iterations; last writes bf16 attn in place over E
    const float* src = xyz;
    float* dsts[5] = {xyzA, xyzB, xyzA, xyzB, outp};
    for (int it = 0; it < 5; it++) {
        ms_iter<<<dim3(2048), blk, 0, stream>>>(Ebf, src, dsts[it], yhat, bwptr,
                                                Ebf, it == 4 ? 1 : 0);
        src = dsts[it];
    }

    // x = attn @ v (MFMA bf16, split-K atomics into zeroed xb)
    hipMemsetAsync(xb, 0, 2048L * 512 * sizeof(float), stream);
    av_mfma<<<dim3(32, 4, 8), blk, 0, stream>>>(Ebf, vT, xb);

    // out = x @ Wo.T + bo
    gemm_nt<<<dim3(32, 8, 1), blk, 0, stream>>>(xb, Wo, bo, outp + 6144);
}

// Round 4
// 372.226 us; speedup vs baseline: 1.8407x; 1.0674x over previous
//
#include <hip/hip_runtime.h>

// Problem constants (fixed by setup_inputs): N=2048, D=512, H=8, dh=64, max_iter=5.
// Identity: exp(s/t + log(kern*yw+eps)) = exp(s/t) * (kern*yw+eps).
// E[n][h*2048+m] = mask ? bf16(exp(s/(8t))) : 0 is loop-invariant (64 MB, L3-resident).
// Row-contiguous layout: one ms_iter block reads one 32 KB contiguous span.

typedef __attribute__((ext_vector_type(8))) short bf16x8;
typedef __attribute__((ext_vector_type(4))) float f32x4;

__device__ __forceinline__ unsigned short f2bf(float f) {
    unsigned int u = __float_as_uint(f);
    u += 0x7fff + ((u >> 16) & 1);   // RNE (inputs finite)
    return (unsigned short)(u >> 16);
}
__device__ __forceinline__ float bf2f(unsigned short u) {
    return __uint_as_float((unsigned int)u << 16);
}

union EU { bf16x8 v; unsigned short u[8]; };

// ---------------------------------------------------------------------------
// Convert strf [1048576] and Wq/Wk/Wv [262144 each] fp32 -> bf16.
// sW is [3][262144] contiguous. 8 elements/thread; grid 896x256 exact.
// ---------------------------------------------------------------------------
__global__ __launch_bounds__(256)
void conv_all(const float* __restrict__ strf,
              const float* __restrict__ Wq, const float* __restrict__ Wk,
              const float* __restrict__ Wv,
              unsigned short* __restrict__ sA, unsigned short* __restrict__ sW)
{
    const long base = (long)(blockIdx.x * 256 + threadIdx.x) * 8;
    const float* src;
    unsigned short* dst;
    if (base < 1048576) {
        src = strf + base; dst = sA + base;
    } else {
        const long rel = base - 1048576;
        const int seg = (int)(rel >> 18);
        const long off = rel & 262143;
        src = (seg == 0 ? Wq : (seg == 1 ? Wk : Wv)) + off;
        dst = sW + (long)seg * 262144 + off;
    }
    float4 a = *reinterpret_cast<const float4*>(src);
    float4 b = *reinterpret_cast<const float4*>(src + 4);
    EU o;
    o.u[0] = f2bf(a.x); o.u[1] = f2bf(a.y); o.u[2] = f2bf(a.z); o.u[3] = f2bf(a.w);
    o.u[4] = f2bf(b.x); o.u[5] = f2bf(b.y); o.u[6] = f2bf(b.z); o.u[7] = f2bf(b.w);
    *reinterpret_cast<bf16x8*>(dst) = o.v;
}

// ---------------------------------------------------------------------------
// q/k/v projection via bf16 MFMA. C[n][d] = sum_k sA[n][k] * W[z][d][k] + b[d].
// grid (32 n-tiles, 8 d-tiles, 3); 4 waves, wave does 16 rows x 64 cols, K=512.
// z=0 -> qh bf16, z=1 -> kh bf16 (LDS roundtrip, coalesced);
// z=2 -> vT bf16 TRANSPOSED direct store (vT[d][m], 8-B per tile-reg group).
// ---------------------------------------------------------------------------
__global__ __launch_bounds__(256)
void qkv_mfma(const unsigned short* __restrict__ sA,
              const unsigned short* __restrict__ sW,
              const float* __restrict__ bq, const float* __restrict__ bk,
              const float* __restrict__ bv,
              unsigned short* __restrict__ qh, unsigned short* __restrict__ kh,
              unsigned short* __restrict__ vT)
{
    const int z  = blockIdx.z;
    const int bx = blockIdx.x;     // n-tile
    const int by = blockIdx.y;     // d-tile
    const int tid = threadIdx.x;
    const int wv = tid >> 6;
    const int lane = tid & 63;
    const int row  = lane & 15;
    const int koct = (lane >> 4) * 8;
    const int n0 = bx * 64;

    const unsigned short* Ap = sA + (long)(n0 + wv * 16 + row) * 512;
    const unsigned short* Bp = sW + (long)z * 262144 + (long)(by * 64 + row) * 512;

    f32x4 acc[4] = {};
#pragma unroll
    for (int k0 = 0; k0 < 512; k0 += 32) {
        bf16x8 a = *reinterpret_cast<const bf16x8*>(Ap + k0 + koct);
#pragma unroll
        for (int t = 0; t < 4; t++) {
            bf16x8 b = *reinterpret_cast<const bf16x8*>(Bp + (long)(t * 16) * 512 + k0 + koct);
            acc[t] = __builtin_amdgcn_mfma_f32_16x16x32_bf16(a, b, acc[t], 0, 0, 0);
        }
    }

    if (z == 2) {
        // direct transposed store: vT[d][m], lane has col d = lane&15 (+16t), rows m consecutive
        const int rbase = n0 + wv * 16 + (lane >> 4) * 4;
#pragma unroll
        for (int t = 0; t < 4; t++) {
            const int d = by * 64 + t * 16 + (lane & 15);
            const float bb = bv[d];
            ushort4 o;
            o.x = f2bf(acc[t][0] + bb); o.y = f2bf(acc[t][1] + bb);
            o.z = f2bf(acc[t][2] + bb); o.w = f2bf(acc[t][3] + bb);
            *reinterpret_cast<ushort4*>(vT + (long)d * 2048 + rbase) = o;
        }
        return;
    }

    __shared__ float ls[64][68];
    const int lrb = wv * 16 + (lane >> 4) * 4;
    const int lcb = lane & 15;
#pragma unroll
    for (int t = 0; t < 4; t++)
#pragma unroll
        for (int r = 0; r < 4; r++)
            ls[lrb + r][t * 16 + lcb] = acc[t][r];
    __syncthreads();

    const float* bias = (z == 0) ? bq : bk;
    unsigned short* dst = (z == 0) ? qh : kh;
    const int r2 = tid >> 2;
    const int c2 = (tid & 3) * 16;
    float sv[16];
#pragma unroll
    for (int j = 0; j < 4; j++) {
        float4 s = *reinterpret_cast<const float4*>(&ls[r2][c2 + j * 4]);
        float4 bb = *reinterpret_cast<const float4*>(bias + by * 64 + c2 + j * 4);
        sv[j*4+0] = s.x + bb.x; sv[j*4+1] = s.y + bb.y;
        sv[j*4+2] = s.z + bb.z; sv[j*4+3] = s.w + bb.w;
    }
    EU o0, o1;
#pragma unroll
    for (int j = 0; j < 8; j++) { o0.u[j] = f2bf(sv[j]); o1.u[j] = f2bf(sv[8 + j]); }
    unsigned short* dp = dst + (long)(n0 + r2) * 512 + by * 64 + c2;
    *reinterpret_cast<bf16x8*>(dp)     = o0.v;
    *reinterpret_cast<bf16x8*>(dp + 8) = o1.v;
}

// ---------------------------------------------------------------------------
// E[n][h*2048+m] = mask ? bf16(exp(scale * q_h[n]·k_h[m])) : 0 via bf16 MFMA.
// grid (16 m-supertiles(128), 32 n-tiles, 8 heads); wave: 16 rows x 128 cols,
// 16 MFMA, q-frag reused 8x. Epilogue in 2 halves through 17 KB LDS.
// ---------------------------------------------------------------------------
__global__ __launch_bounds__(256)
void scores_mfma(const unsigned short* __restrict__ qh,
                 const unsigned short* __restrict__ kh,
                 const int* __restrict__ dmask,
                 const float* __restrict__ tptr,
                 unsigned short* __restrict__ Ebf)
{
    const int h  = blockIdx.z;
    const int m0 = blockIdx.x * 128;
    const int n0 = blockIdx.y * 64;
    const int tid = threadIdx.x;
    const int wv = tid >> 6;
    const int lane = tid & 63;
    const float scale = 1.0f / (8.0f * tptr[0]);

    const int row  = lane & 15;
    const int koct = (lane >> 4) * 8;
    const unsigned short* Aq = qh + (long)(n0 + wv * 16 + row) * 512 + h * 64;
    const unsigned short* Bk = kh + (long)(m0 + row) * 512 + h * 64;

    f32x4 acc[8] = {};
#pragma unroll
    for (int k0 = 0; k0 < 64; k0 += 32) {
        bf16x8 a = *reinterpret_cast<const bf16x8*>(Aq + k0 + koct);
#pragma unroll
        for (int t = 0; t < 8; t++) {
            bf16x8 b = *reinterpret_cast<const bf16x8*>(Bk + (long)(t * 16) * 512 + k0 + koct);
            acc[t] = __builtin_amdgcn_mfma_f32_16x16x32_bf16(a, b, acc[t], 0, 0, 0);
        }
    }

    __shared__ float ls[64][68];
    const int lrb = wv * 16 + (lane >> 4) * 4;
    const int lcb = lane & 15;
    const int r2 = tid >> 2;
    const int c2 = (tid & 3) * 16;
    const int gn = n0 + r2;

#pragma unroll
    for (int half = 0; half < 2; half++) {
#pragma unroll
        for (int t = 0; t < 4; t++)
#pragma unroll
            for (int r = 0; r < 4; r++)
                ls[lrb + r][t * 16 + lcb] = acc[half * 4 + t][r];
        __syncthreads();

        const int mcol = m0 + half * 64 + c2;
        const int* mp = dmask + (long)gn * 2048 + mcol;
        int4 mk0 = reinterpret_cast<const int4*>(mp)[0];
        int4 mk1 = reinterpret_cast<const int4*>(mp)[1];
        int4 mk2 = reinterpret_cast<const int4*>(mp)[2];
        int4 mk3 = reinterpret_cast<const int4*>(mp)[3];
        int mk[16] = {mk0.x, mk0.y, mk0.z, mk0.w, mk1.x, mk1.y, mk1.z, mk1.w,
                      mk2.x, mk2.y, mk2.z, mk2.w, mk3.x, mk3.y, mk3.z, mk3.w};
        float4 s0 = *reinterpret_cast<const float4*>(&ls[r2][c2 + 0]);
        float4 s1 = *reinterpret_cast<const float4*>(&ls[r2][c2 + 4]);
        float4 s2 = *reinterpret_cast<const float4*>(&ls[r2][c2 + 8]);
        float4 s3 = *reinterpret_cast<const float4*>(&ls[r2][c2 + 12]);
        float sv[16] = {s0.x, s0.y, s0.z, s0.w, s1.x, s1.y, s1.z, s1.w,
                        s2.x, s2.y, s2.z, s2.w, s3.x, s3.y, s3.z, s3.w};
        EU o0, o1;
#pragma unroll
        for (int j = 0; j < 8; j++)
            o0.u[j] = (mk[j] > 0) ? f2bf(__expf(sv[j] * scale)) : (unsigned short)0;
#pragma unroll
        for (int j = 0; j < 8; j++)
            o1.u[j] = (mk[8 + j] > 0) ? f2bf(__expf(sv[8 + j] * scale)) : (unsigned short)0;
        unsigned short* ep = Ebf + (long)gn * 16384 + h * 2048 + mcol;
        *reinterpret_cast<bf16x8*>(ep)     = o0.v;
        *reinterpret_cast<bf16x8*>(ep + 8) = o1.v;
        __syncthreads();
    }
}

// ---------------------------------------------------------------------------
// One mean-shift iteration. Block = row n, 256 threads; thread owns
// m = tid*8..+8 for all 8 heads (block reads one contiguous 32 KB span of E).
// ---------------------------------------------------------------------------
__global__ __launch_bounds__(256)
void ms_iter(const unsigned short* __restrict__ Ebf,
             const float* __restrict__ xyz_src,
             float* __restrict__ xyz_dst,
             const float* __restrict__ y_hat,
             const float* __restrict__ bwp,
             unsigned short* __restrict__ attn_out,
             int write_attn)
{
    const int n = blockIdx.x;
    const int tid = threadIdx.x;
    const int lane = tid & 63;
    const int wave = tid >> 6;
    const int m0 = tid * 8;

    __shared__ float red[64];

    const float bw = bwp[0];
    const float c2k = 1.0f / (2.0f * bw * bw);

    const float xn = xyz_src[n * 3 + 0];
    const float yn = xyz_src[n * 3 + 1];
    const float zn = xyz_src[n * 3 + 2];
    const float sqn = xn * xn + yn * yn + zn * zn;

    float mx[8], my[8], mz[8];
    {
        const float4* xp = reinterpret_cast<const float4*>(xyz_src + (long)m0 * 3);
        float4 a = xp[0], b = xp[1], c = xp[2], d = xp[3], e = xp[4], f = xp[5];
        mx[0]=a.x; my[0]=a.y; mz[0]=a.z;  mx[1]=a.w; my[1]=b.x; mz[1]=b.y;
        mx[2]=b.z; my[2]=b.w; mz[2]=c.x;  mx[3]=c.y; my[3]=c.z; mz[3]=c.w;
        mx[4]=d.x; my[4]=d.y; mz[4]=d.z;  mx[5]=d.w; my[5]=e.x; mz[5]=e.y;
        mx[6]=e.z; my[6]=e.w; mz[6]=f.x;  mx[7]=f.y; my[7]=f.z; mz[7]=f.w;
    }
    float4 yh0 = *reinterpret_cast<const float4*>(y_hat + m0);
    float4 yh1 = *reinterpret_cast<const float4*>(y_hat + m0 + 4);
    float yh[8] = {yh0.x, yh0.y, yh0.z, yh0.w, yh1.x, yh1.y, yh1.z, yh1.w};

    float g[8];
#pragma unroll
    for (int j = 0; j < 8; j++) {
        const float d2 = sqn + (mx[j]*mx[j] + my[j]*my[j] + mz[j]*mz[j])
                       - 2.0f * (xn*mx[j] + yn*my[j] + zn*mz[j]);
        g[j] = __expf(-d2 * c2k) * yh[j] + 1e-9f;
    }

    const unsigned short* Ep = Ebf + (long)n * 16384 + m0;
    EU E[8];
#pragma unroll
    for (int h = 0; h < 8; h++)
        E[h].v = *reinterpret_cast<const bf16x8*>(Ep + h * 2048);

    float z[8];
#pragma unroll
    for (int h = 0; h < 8; h++) {
        float zz = 0.f;
#pragma unroll
        for (int j = 0; j < 8; j++) zz += bf2f(E[h].u[j]) * g[j];
        z[h] = zz;
    }

#pragma unroll
    for (int h = 0; h < 8; h++) {
        float v = z[h];
#pragma unroll
        for (int off = 32; off > 0; off >>= 1) v += __shfl_down(v, off, 64);
        if (lane == 0) red[wave * 8 + h] = v;
    }
    __syncthreads();
    if (tid < 8) {
        const float s = red[tid] + red[8 + tid] + red[16 + tid] + red[24 + tid];
        red[32 + tid] = 1.0f / s;
    }
    __syncthreads();
    float invz[8];
#pragma unroll
    for (int h = 0; h < 8; h++) invz[h] = red[32 + h];
    __syncthreads();

    float ax = 0.f, ay = 0.f, az = 0.f;
#pragma unroll
    for (int j = 0; j < 8; j++) {
        float w = 0.f;
#pragma unroll
        for (int h = 0; h < 8; h++) w += bf2f(E[h].u[j]) * invz[h];
        w *= 0.125f * g[j];
        ax += w * mx[j]; ay += w * my[j]; az += w * mz[j];
    }
    if (write_attn) {
        unsigned short* ap = attn_out + (long)n * 16384 + m0;
#pragma unroll
        for (int h = 0; h < 8; h++) {
            EU o;
#pragma unroll
            for (int j = 0; j < 8; j++)
                o.u[j] = f2bf(bf2f(E[h].u[j]) * g[j] * invz[h]);
            *reinterpret_cast<bf16x8*>(ap + h * 2048) = o.v;
        }
    }

    float v3[3] = {ax, ay, az};
#pragma unroll
    for (int c = 0; c < 3; c++) {
        float v = v3[c];
#pragma unroll
        for (int off = 32; off > 0; off >>= 1) v += __shfl_down(v, off, 64);
        if (lane == 0) red[c * 4 + wave] = v;
    }
    __syncthreads();
    if (tid < 3) {
        xyz_dst[n * 3 + tid] = red[tid * 4 + 0] + red[tid * 4 + 1] +
                               red[tid * 4 + 2] + red[tid * 4 + 3];
    }
}

// ---------------------------------------------------------------------------
// x = attn @ v via MFMA bf16. attn layout [n][h*2048+m].
// grid (32 row-tiles, 4 K-splits, 8 heads); fp32 atomicAdd into zeroed xb.
// ---------------------------------------------------------------------------
__global__ __launch_bounds__(256)
void av_mfma(const unsigned short* __restrict__ attn,  // [2048][8*2048] bf16
             const unsigned short* __restrict__ vT,    // [512][2048] bf16
             float* __restrict__ xb)                   // [2048][512] fp32, zeroed
{
    const int h  = blockIdx.z;
    const int s  = blockIdx.y;
    const int bx = blockIdx.x;
    const int wv = threadIdx.x >> 6;
    const int lane = threadIdx.x & 63;
    const int n0 = bx * 64 + wv * 16;
    const int kc = s * 512;

    const int mrow = lane & 15;
    const int koct = (lane >> 4) * 8;

    const unsigned short* Ab = attn + (long)(n0 + mrow) * 16384 + h * 2048;
    const unsigned short* Bb = vT + ((long)h * 64 + mrow) * 2048;

    f32x4 acc[4] = {};
    for (int k0 = kc; k0 < kc + 512; k0 += 32) {
        bf16x8 a = *reinterpret_cast<const bf16x8*>(Ab + k0 + koct);
#pragma unroll
        for (int t = 0; t < 4; t++) {
            bf16x8 b = *reinterpret_cast<const bf16x8*>(Bb + (long)(t * 16) * 2048 + k0 + koct);
            acc[t] = __builtin_amdgcn_mfma_f32_16x16x32_bf16(a, b, acc[t], 0, 0, 0);
        }
    }

    const int rbase = n0 + (lane >> 4) * 4;
    const int dcol = lane & 15;
#pragma unroll
    for (int t = 0; t < 4; t++)
#pragma unroll
        for (int r = 0; r < 4; r++)
            atomicAdd(&xb[(long)(rbase + r) * 512 + h * 64 + t * 16 + dcol], acc[t][r]);
}

// ---------------------------------------------------------------------------
// GEMM NT fp32 (out projection): C = A @ Wo.T + bo
// ---------------------------------------------------------------------------
__global__ __launch_bounds__(256)
void gemm_nt(const float* __restrict__ A,
             const float* __restrict__ B,
             const float* __restrict__ bias,
             float* __restrict__ C)
{
    __shared__ float As[16][68];
    __shared__ float Bs[16][68];

    const int tid = threadIdx.x;
    const int i0 = blockIdx.x * 64;
    const int j0 = blockIdx.y * 64;
    const int tx = tid & 15, ty = tid >> 4;
    const int lr = tid >> 2;
    const int lc = (tid & 3) << 2;

    float acc[4][4] = {};

    for (int k0 = 0; k0 < 512; k0 += 16) {
        float4 av = *reinterpret_cast<const float4*>(A + (long)(i0 + lr) * 512 + (k0 + lc));
        float4 bv = *reinterpret_cast<const float4*>(B + (long)(j0 + lr) * 512 + (k0 + lc));
        As[lc + 0][lr] = av.x; As[lc + 1][lr] = av.y; As[lc + 2][lr] = av.z; As[lc + 3][lr] = av.w;
        Bs[lc + 0][lr] = bv.x; Bs[lc + 1][lr] = bv.y; Bs[lc + 2][lr] = bv.z; Bs[lc + 3][lr] = bv.w;
        __syncthreads();
#pragma unroll
        for (int kk = 0; kk < 16; kk++) {
            float4 a = *reinterpret_cast<const float4*>(&As[kk][ty << 2]);
            float4 b = *reinterpret_cast<const float4*>(&Bs[kk][tx << 2]);
            float ar[4] = {a.x, a.y, a.z, a.w};
            float br[4] = {b.x, b.y, b.z, b.w};
#pragma unroll
            for (int p = 0; p < 4; p++)
#pragma unroll
                for (int q = 0; q < 4; q++)
                    acc[p][q] += ar[p] * br[q];
        }
        __syncthreads();
    }

#pragma unroll
    for (int p = 0; p < 4; p++) {
        const int row = i0 + (ty << 2) + p;
        const int col = j0 + (tx << 2);
        float4 o;
        o.x = acc[p][0] + bias[col + 0];
        o.y = acc[p][1] + bias[col + 1];
        o.z = acc[p][2] + bias[col + 2];
        o.w = acc[p][3] + bias[col + 3];
        *reinterpret_cast<float4*>(C + (long)row * 512 + col) = o;
    }
}

// ---------------------------------------------------------------------------
extern "C" void kernel_launch(void* const* d_in, const int* in_sizes, int n_in,
                              void* d_out, int out_size, void* d_ws, size_t ws_size,
                              hipStream_t stream)
{
    (void)in_sizes; (void)n_in; (void)out_size; (void)ws_size;

    const float* xyz   = (const float*)d_in[0];
    const float* strf  = (const float*)d_in[1];
    // d_in[2] esm_feat: dead code (DCE'd in reference)
    const float* yhat  = (const float*)d_in[3];
    const int*   dmask = (const int*)d_in[4];
    const float* tptr  = (const float*)d_in[5];
    const float* bwptr = (const float*)d_in[6];
    // d_in[7] max_iter = 5 (fixed)
    const float* Wq = (const float*)d_in[8];
    const float* bq = (const float*)d_in[9];
    const float* Wk = (const float*)d_in[10];
    const float* bk = (const float*)d_in[11];
    const float* Wv = (const float*)d_in[12];
    const float* bv = (const float*)d_in[13];
    const float* Wo = (const float*)d_in[14];
    const float* bo = (const float*)d_in[15];
    float* outp = (float*)d_out;

    char* wsb = (char*)d_ws;
    float* xb            = (float*)(wsb);                      // 4 MB fp32 acc
    unsigned short* sA   = (unsigned short*)(wsb + (4L << 20));  // strf bf16, 2 MB
    unsigned short* sW   = (unsigned short*)(wsb + (6L << 20));  // Wq|Wk|Wv bf16, 1.5 MB
    unsigned short* qh   = (unsigned short*)(wsb + (8L << 20));  // 2 MB
    unsigned short* kh   = (unsigned short*)(wsb + (10L << 20)); // 2 MB
    unsigned short* vT   = (unsigned short*)(wsb + (12L << 20)); // 2 MB
    float* xyzA          = (float*)(wsb + (14L << 20));
    float* xyzB          = xyzA + 8192;
    unsigned short* Ebf  = (unsigned short*)(wsb + (16L << 20)); // [2048][16384] bf16, 64 MB

    dim3 blk(256, 1, 1);

    // bf16 conversions + fused q/k/v MFMA projections (v stored transposed)
    conv_all<<<dim3(896), blk, 0, stream>>>(strf, Wq, Wk, Wv, sA, sW);
    qkv_mfma<<<dim3(32, 8, 3), blk, 0, stream>>>(sA, sW, bq, bk, bv, qh, kh, vT);

    // E = mask ? exp(q·k/(8t)) : 0, bf16, layout [n][h*2048+m]
    scores_mfma<<<dim3(16, 32, 8), blk, 0, stream>>>(qh, kh, dmask, tptr, Ebf);

    // 5 mean-shift iterations; last writes bf16 attn in place over E
    const float* src = xyz;
    float* dsts[5] = {xyzA, xyzB, xyzA, xyzB, outp};
    for (int it = 0; it < 5; it++) {
        ms_iter<<<dim3(2048), blk, 0, stream>>>(Ebf, src, dsts[it], yhat, bwptr,
                                                Ebf, it == 4 ? 1 : 0);
        src = dsts[it];
    }

    // x = attn @ v (MFMA bf16, split-K atomics into zeroed xb)
    hipMemsetAsync(xb, 0, 2048L * 512 * sizeof(float), stream);
    av_mfma<<<dim3(32, 4, 8), blk, 0, stream>>>(Ebf, vT, xb);

    // out = x @ Wo.T + bo
    gemm_nt<<<dim3(32, 8, 1), blk, 0, stream>>>(xb, Wo, bo, outp + 6144);
}